// Round 15
// baseline (790.166 us; speedup 1.0000x reference)
//
#include <hip/hip_runtime.h>
#include <math.h>

#define T_DIM 512
#define B_DIM 256
#define D_DIM 256
#define H_DIM 256
#define G_DIM 1024   // 4*H
#define K_DIM 512    // D + H
#define NROUNDS 40
#define CHAIN_K 16   // rounds 0..15 batched; steps >=16 via per-segment finisher

typedef __attribute__((ext_vector_type(8))) short short8;
typedef __attribute__((ext_vector_type(4))) float f32x4;

__device__ __forceinline__ unsigned int f2bf(float f) {
    unsigned int b = __float_as_uint(f);
    return (b + 0x7FFFu + ((b >> 16) & 1u)) >> 16;   // round-to-nearest-even bf16
}
__device__ __forceinline__ unsigned long long pack4(float4 v) {
    const unsigned int lo = (f2bf(v.y) << 16) | f2bf(v.x);
    const unsigned int hi = (f2bf(v.w) << 16) | f2bf(v.z);
    return ((unsigned long long)hi << 32) | lo;
}
__device__ __forceinline__ float sigm(float x) { return 1.0f / (1.0f + __expf(-x)); }
__device__ __forceinline__ float tanh_fast(float x) { return 2.0f / (1.0f + __expf(-2.0f * x)) - 1.0f; }

// async 16B/lane global->LDS (dest = wave-uniform base + lane*16; SOURCE is per-lane)
__device__ __forceinline__ void dma16(const void* g, void* l) {
    __builtin_amdgcn_global_load_lds(
        (const __attribute__((address_space(1))) void*)g,
        (__attribute__((address_space(3))) void*)l, 16, 0, 0);
}

// Prepack W into MFMA B-fragment order, bf16.
// short idx ((nt*16+ks)*64+l)*8+j  <->  g = nt*16+(l&15), k = ks*32+((l>>4)<<3)+j
__global__ __launch_bounds__(256) void k_prep_weights(
    const float* __restrict__ W_ih, const float* __restrict__ W_hh,
    const float* __restrict__ b_ih, const float* __restrict__ b_hh,
    unsigned int* __restrict__ Wb, float* __restrict__ bias)
{
    const int idx = blockIdx.x * 256 + threadIdx.x;   // 0 .. 262143
    const int jp = idx & 3, l = (idx >> 2) & 63, ks = (idx >> 8) & 15, nt = idx >> 12;
    const int g = nt * 16 + (l & 15);
    const int k0 = ks * 32 + ((l >> 4) << 3) + 2 * jp;
    const float w0 = (k0 < D_DIM) ? W_ih[g * D_DIM + k0] : W_hh[g * H_DIM + (k0 - D_DIM)];
    const float w1 = (k0 + 1 < D_DIM) ? W_ih[g * D_DIM + k0 + 1] : W_hh[g * H_DIM + (k0 + 1 - D_DIM)];
    Wb[idx] = (f2bf(w1) << 16) | f2bf(w0);
    if (idx < G_DIM) bias[idx] = b_ih[idx] + b_hh[idx];
}

// Prepack W k-major for the finisher GEMV.
__global__ __launch_bounds__(256) void k_prep_wq(
    const float* __restrict__ W_ih, const float* __restrict__ W_hh,
    unsigned long long* __restrict__ Wq)
{
    const int idx = blockIdx.x * 256 + threadIdx.x;   // 0..131071
    const int kq = idx >> 10, g = idx & (G_DIM - 1);
    float w[4];
    #pragma unroll
    for (int j = 0; j < 4; ++j) {
        const int k = kq * 4 + j;
        w[j] = (k < D_DIM) ? W_ih[g * D_DIM + k] : W_hh[g * H_DIM + (k - D_DIM)];
    }
    Wq[idx] = pack4((float4){w[0], w[1], w[2], w[3]});
}

// ab x-half: ab[pos*512 + k] = bf16(x[pos][k]), k 0..255 (linear order).
__global__ __launch_bounds__(256) void k_prep_ab(
    const float* __restrict__ x, unsigned long long* __restrict__ ab_u64)
{
    const int idx = blockIdx.x * 256 + threadIdx.x;      // (pos, 16B chunk): TB*64
    const int pos = idx >> 6, ch = idx & 63;             // ch < 32 -> x half only
    if (ch >= 32) return;
    const float4 v0 = *(const float4*)(x + (size_t)pos * D_DIM + ch * 8);
    const float4 v1 = *(const float4*)(x + (size_t)pos * D_DIM + ch * 8 + 4);
    ab_u64[(size_t)pos * 128 + ch * 2]     = pack4(v0);
    ab_u64[(size_t)pos * 128 + ch * 2 + 1] = pack4(v1);
}

// ab h-half prefill for reset rows (done==1 -> 0) and t==0 (!done -> h0).
__global__ __launch_bounds__(256) void k_prefill(
    const float* __restrict__ h0, const int* __restrict__ done,
    unsigned long long* __restrict__ ab_u64)
{
    const int idx = blockIdx.x * 256 + threadIdx.x;      // (pos, chunk32): TB*32
    const int pos = idx >> 5, ch = idx & 31;
    const int d = done[pos];
    if (!d && pos >= B_DIM) return;                      // not a reset row
    unsigned long long v0 = 0ull, v1 = 0ull;
    if (!d) {                                            // t==0, use h0
        const float4 a = *(const float4*)(h0 + (size_t)(pos & (B_DIM - 1)) * H_DIM + ch * 8);
        const float4 b = *(const float4*)(h0 + (size_t)(pos & (B_DIM - 1)) * H_DIM + ch * 8 + 4);
        v0 = pack4(a); v1 = pack4(b);
    }
    ab_u64[(size_t)pos * 128 + 64 + ch * 2]     = v0;
    ab_u64[(size_t)pos * 128 + 64 + ch * 2 + 1] = v1;
}

// Parallel kmap + per-block bin counts (kmap = TRUE steps since reset; bins clamp).
__global__ __launch_bounds__(256) void k_kmap(
    const int* __restrict__ done, int* __restrict__ kmap, int* __restrict__ bcnt)
{
    __shared__ int lcnt[NROUNDS];
    const int tid = threadIdx.x;
    if (tid < NROUNDS) lcnt[tid] = 0;
    __syncthreads();
    const int t = blockIdx.x, b = tid;
    int kv = t;
    for (int tt = t; tt >= 0; --tt) {
        if (done[tt * B_DIM + b]) { kv = t - tt; break; }
    }
    kmap[t * B_DIM + b] = kv;
    const int bin = kv < NROUNDS ? kv : NROUNDS - 1;
    atomicAdd(&lcnt[bin], 1);
    __syncthreads();
    if (tid < NROUNDS) bcnt[t * NROUNDS + tid] = lcnt[tid];
}

// Exclusive scan of bcnt over t per bin -> boffs; totals -> counts, offs. One block.
__global__ __launch_bounds__(512) void k_scan(
    const int* __restrict__ bcnt, int* __restrict__ boffs,
    int* __restrict__ counts, int* __restrict__ offs)
{
    __shared__ int tmp[512];
    __shared__ int tot[NROUNDS];
    const int t = threadIdx.x;
    for (int bin = 0; bin < NROUNDS; ++bin) {
        const int v = bcnt[t * NROUNDS + bin];
        tmp[t] = v;
        __syncthreads();
        for (int d = 1; d < 512; d <<= 1) {
            const int add = (t >= d) ? tmp[t - d] : 0;
            __syncthreads();
            tmp[t] += add;
            __syncthreads();
        }
        boffs[t * NROUNDS + bin] = tmp[t] - v;   // exclusive
        if (t == 511) tot[bin] = tmp[511];
        __syncthreads();
    }
    if (t == 0) {
        int s = 0;
        for (int i = 0; i < NROUNDS; ++i) { counts[i] = tot[i]; offs[i] = s; s += tot[i]; }
    }
}

// Deterministic pos-sorted scatter (no atomics): rank = #earlier same-bin in block.
__global__ __launch_bounds__(256) void k_scatter(
    const int* __restrict__ kmap, const int* __restrict__ offs,
    const int* __restrict__ boffs, int* __restrict__ rowlist)
{
    __shared__ int bins[256];
    const int t = blockIdx.x, tid = threadIdx.x;
    const int pos = t * 256 + tid;
    const int kv = kmap[pos];
    const int bin = kv < NROUNDS ? kv : NROUNDS - 1;
    bins[tid] = bin;
    __syncthreads();
    int rank = 0;
    for (int i = 0; i < 256; ++i)
        rank += (i < tid && bins[i] == bin) ? 1 : 0;
    rowlist[offs[bin] + boffs[t * NROUNDS + bin] + rank] = pos;
}

// ================== B-resident round (1 nt/wave, sorted rows, counted waits) ==================
// 8 col-blocks (cb) of 128 gates = 32 units x 4 gates. Block 512 thr (8 waves).
// Wave w owns nt = (w>>1)*16 + cb*2 + (w&1): breg[16] = 64 VGPR, truly resident
// (budget: 64 breg + 8 acc + ~120 < 256 at 2 waves/SIMD).
// A: 32-row tiles from ab (1KB/row, XOR src-swizzle by r&15), dbuf 2x32KB.
// Gate exchange scr[4][32][33] f32 (16.9KB, conflict-free pad 33).
// Bottom-wait vmcnt(4): stores (>=4, issued after the 4 A-DMAs) stay in flight.
__global__ __launch_bounds__(512, 1) void k_round(
    const short* __restrict__ ab, const float* __restrict__ c0,
    const int* __restrict__ done,
    const short* __restrict__ Wb, const float* __restrict__ bias,
    const int* __restrict__ counts, const int* __restrict__ offs,
    const int* __restrict__ rowlist,
    float* __restrict__ out, float* __restrict__ c_buf,
    short* __restrict__ ab_w, int kk)
{
    __shared__ short A_lds[2 * 32 * 512];        // 64 KiB
    __shared__ float scr[4 * 32 * 33];           // 16.9 KiB
    const int nk = counts[kk];
    const int base = offs[kk];
    const int ntiles = (nk + 31) >> 5;

    int cb, rt, rstride;
    if (gridDim.x == 256) {                      // XCD map: 8 cbs of a row-chain share XCD
        const int xcd = blockIdx.x & 7, slot = blockIdx.x >> 3;   // slot 0..31
        cb = slot & 7;
        rt = xcd * 4 + (slot >> 3);
        rstride = 32;
    } else {
        cb = blockIdx.x & 7;
        rt = blockIdx.x >> 3;
        rstride = gridDim.x >> 3;
    }
    if (rt >= ntiles) return;                    // block-uniform exit

    const int tid = threadIdx.x;
    const int w = tid >> 6, l = tid & 63;
    const int lr = l >> 4, lc = l & 15;

    const int u_loc = tid & 31;                  // epilogue unit within block
    const int u_ep = cb * 32 + u_loc;
    const int rbase = (tid >> 5) * 2;            // epilogue rows rbase, rbase+1
    const float bI = bias[u_ep], bF = bias[256 + u_ep], bG = bias[512 + u_ep], bO = bias[768 + u_ep];

#define ISSUE_A(row0v, bufv)                                                     \
    {                                                                            \
        _Pragma("unroll") for (int rr = 0; rr < 4; ++rr) {                       \
            const int r_ = w * 4 + rr;                                           \
            const int gr_ = (row0v) + r_;                                        \
            if (gr_ < nk) {                                                      \
                const int p_ = rowlist[base + gr_];                              \
                dma16(ab + (size_t)p_ * 512 + ((l ^ (r_ & 15)) << 3),            \
                      &A_lds[(bufv) * 16384 + r_ * 512]);                        \
            }                                                                    \
        }                                                                        \
    }
#define LOAD_NEXT(row0v, PP, CP, DN, DS)                                         \
    {                                                                            \
        _Pragma("unroll") for (int j_ = 0; j_ < 2; ++j_) {                       \
            const int gr_ = (row0v) + rbase + j_;                                \
            PP[j_] = rowlist[base + (gr_ < nk ? gr_ : nk - 1)];                  \
        }                                                                        \
        _Pragma("unroll") for (int j_ = 0; j_ < 2; ++j_) {                       \
            const int p_ = PP[j_];                                               \
            if (kk > 0) {                                                        \
                CP[j_] = c_buf[(size_t)(p_ - B_DIM) * H_DIM + u_ep];             \
                DN[j_] = 0;                                                      \
            } else {                                                             \
                DN[j_] = done[p_];                                               \
                CP[j_] = c0[(size_t)(p_ & (B_DIM - 1)) * H_DIM + u_ep];          \
            }                                                                    \
            const int sp_ = p_ + B_DIM;                                          \
            DS[j_] = (sp_ < T_DIM * B_DIM) ? done[sp_] : 1;                      \
        }                                                                        \
    }

    // ---- prologue: tile0 state + A-DMA + resident B ----
    int posC[2], dnC[2], dsC[2]; float cpC[2];
    LOAD_NEXT(rt * 32, posC, cpC, dnC, dsC);
    ISSUE_A(rt * 32, 0);
    short8 breg[16];
    {
        const int nt = (w >> 1) * 16 + cb * 2 + (w & 1);
        #pragma unroll
        for (int ks = 0; ks < 16; ++ks)
            breg[ks] = *(const short8*)(Wb + (((size_t)nt * 16 + ks) * 64 + l) * 8);
        #pragma unroll
        for (int ks = 0; ks < 16; ++ks)
            asm volatile("" : "+v"(breg[ks]));
    }
    asm volatile("s_waitcnt vmcnt(0) lgkmcnt(0)" ::: "memory");
    __builtin_amdgcn_sched_barrier(0);
    __builtin_amdgcn_s_barrier();
    __builtin_amdgcn_sched_barrier(0);

    int buf = 0;
    for (; rt < ntiles; rt += rstride) {
        const int row0 = rt * 32;
        const int rtn = rt + rstride;
        const bool more = (rtn < ntiles);

        // issue next tile's gather + A-DMA first (latency hides under MFMA)
        int posN[2], dnN[2], dsN[2]; float cpN[2];
        if (more) {
            LOAD_NEXT(rtn * 32, posN, cpN, dnN, dsN);
            ISSUE_A(rtn * 32, buf ^ 1);
        }

        // compute: 32 MFMA from LDS-A x resident-B
        f32x4 acc[2];
        acc[0] = (f32x4){0, 0, 0, 0};
        acc[1] = (f32x4){0, 0, 0, 0};
        #pragma unroll
        for (int ks = 0; ks < 16; ++ks) {
            #pragma unroll
            for (int mb = 0; mb < 2; ++mb) {
                const short8 a = *(const short8*)&A_lds[buf * 16384 + (mb * 16 + lc) * 512
                                                       + (((ks * 4 + lr) ^ lc) << 3)];
                acc[mb] = __builtin_amdgcn_mfma_f32_16x16x32_bf16(a, breg[ks], acc[mb], 0, 0, 0);
            }
        }

        // gate exchange: scr[gt][u_loc 32][row 33]
        {
            const int gidx = (w >> 1) * 32 + (w & 1) * 16 + lc;
            *(f32x4*)&scr[gidx * 33 + 0 * 16 + lr * 4] = acc[0];
            *(f32x4*)&scr[gidx * 33 + 1 * 16 + lr * 4] = acc[1];
        }
        asm volatile("s_waitcnt lgkmcnt(0)" ::: "memory");
        __builtin_amdgcn_sched_barrier(0);
        __builtin_amdgcn_s_barrier();
        __builtin_amdgcn_sched_barrier(0);

        // epilogue: load-free LSTM pointwise; thread = (u_loc, rows rbase..rbase+1)
        #pragma unroll
        for (int j = 0; j < 2; ++j) {
            const int gr = row0 + rbase + j;
            if (gr < nk) {
                const int r = rbase + j;
                const float vi = scr[(0 * 32 + u_loc) * 33 + r];
                const float vf = scr[(1 * 32 + u_loc) * 33 + r];
                const float vg = scr[(2 * 32 + u_loc) * 33 + r];
                const float vo = scr[(3 * 32 + u_loc) * 33 + r];
                const int pos = posC[j];
                const float cp = dnC[j] ? 0.0f : cpC[j];
                const float si = sigm(vi + bI);
                const float sf = sigm(vf + bF);
                const float tg = tanh_fast(vg + bG);
                const float so = sigm(vo + bO);
                const float cn = sf * cp + si * tg;
                const float hn = so * tanh_fast(cn);
                c_buf[(size_t)pos * H_DIM + u_ep] = cn;
                out[(size_t)pos * H_DIM + u_ep]  = hn;
                if (kk + 1 < CHAIN_K && !dsC[j])
                    ab_w[(size_t)(pos + B_DIM) * 512 + 256 + u_ep] = (short)f2bf(hn);
            }
        }

        // bottom: wait next-A DMAs (behind them: >=4 c/out stores stay in flight)
        asm volatile("s_waitcnt vmcnt(4) lgkmcnt(0)" ::: "memory");
        __builtin_amdgcn_sched_barrier(0);
        __builtin_amdgcn_s_barrier();
        __builtin_amdgcn_sched_barrier(0);

        posC[0] = posN[0]; posC[1] = posN[1];
        cpC[0] = cpN[0];  cpC[1] = cpN[1];
        dnC[0] = dnN[0];  dnC[1] = dnN[1];
        dsC[0] = dsN[0];  dsC[1] = dsN[1];
        buf ^= 1;
    }
#undef ISSUE_A
#undef LOAD_NEXT
}

// Per-segment sequential finisher for steps >= CHAIN_K (independent chains).
__global__ __launch_bounds__(1024) void k_finish(
    const float* __restrict__ x, const unsigned long long* __restrict__ Wq,
    const float* __restrict__ bias,
    const int* __restrict__ counts, const int* __restrict__ offs,
    const int* __restrict__ rowlist, const int* __restrict__ kmap,
    float* __restrict__ out, float* __restrict__ c_buf)
{
    __shared__ float abuf[K_DIM];
    __shared__ float dots[G_DIM];
    const int g = threadIdx.x;
    const int nch = counts[CHAIN_K];

    for (int m = blockIdx.x; m < nch; m += gridDim.x) {
        const int pos0 = rowlist[offs[CHAIN_K] + m];
        float c_u = 0.0f;
        if (g < H_DIM) {
            abuf[H_DIM + g] = out[(size_t)(pos0 - B_DIM) * H_DIM + g];
            c_u = c_buf[(size_t)(pos0 - B_DIM) * H_DIM + g];
        }
        int pos = pos0, step = CHAIN_K;
        while (true) {
            if (g < H_DIM) abuf[g] = x[(size_t)pos * D_DIM + g];
            __syncthreads();
            float dot = bias[g];
            #pragma unroll 8
            for (int kq = 0; kq < K_DIM / 4; ++kq) {
                const unsigned long long wq = Wq[(size_t)kq * G_DIM + g];
                const float4 a = *(const float4*)&abuf[kq * 4];
                const unsigned int wlo = (unsigned int)wq;
                const unsigned int whi = (unsigned int)(wq >> 32);
                const float w0 = __uint_as_float(wlo << 16);
                const float w1 = __uint_as_float(wlo & 0xFFFF0000u);
                const float w2 = __uint_as_float(whi << 16);
                const float w3 = __uint_as_float(whi & 0xFFFF0000u);
                dot = fmaf(a.x, w0, dot);
                dot = fmaf(a.y, w1, dot);
                dot = fmaf(a.z, w2, dot);
                dot = fmaf(a.w, w3, dot);
            }
            dots[g] = dot;
            __syncthreads();
            if (g < H_DIM) {
                const float si = sigm(dots[g]);
                const float sf = sigm(dots[H_DIM + g]);
                const float tg = tanh_fast(dots[2 * H_DIM + g]);
                const float so = sigm(dots[3 * H_DIM + g]);
                c_u = sf * c_u + si * tg;
                const float hn = so * tanh_fast(c_u);
                out[(size_t)pos * H_DIM + g]   = hn;
                c_buf[(size_t)pos * H_DIM + g] = c_u;
                abuf[H_DIM + g] = hn;
            }
            pos += B_DIM;
            ++step;
            __syncthreads();
            if (pos >= T_DIM * B_DIM) break;
            if (kmap[pos] != step) break;
        }
        __syncthreads();
    }
}

__global__ __launch_bounds__(256) void k_final(const float* __restrict__ c_buf, float* __restrict__ out)
{
    const size_t i = (size_t)blockIdx.x * 256 + threadIdx.x;
    const size_t featN = (size_t)T_DIM * B_DIM * H_DIM;
    const size_t last  = (size_t)(T_DIM - 1) * B_DIM * H_DIM;
    out[featN + i] = out[last + i];
    out[featN + (size_t)B_DIM * H_DIM + i] = c_buf[last + i];
}

extern "C" void kernel_launch(void* const* d_in, const int* in_sizes, int n_in,
                              void* d_out, int out_size, void* d_ws, size_t ws_size,
                              hipStream_t stream)
{
    const float* x    = (const float*)d_in[0];
    const float* h0   = (const float*)d_in[1];
    const float* c0   = (const float*)d_in[2];
    const float* W_ih = (const float*)d_in[3];
    const float* W_hh = (const float*)d_in[4];
    const float* b_ih = (const float*)d_in[5];
    const float* b_hh = (const float*)d_in[6];
    const int*   done = (const int*)d_in[7];
    float* out = (float*)d_out;

    const size_t TB = (size_t)T_DIM * B_DIM;
    char* ws = (char*)d_ws;
    size_t off = 0;
    float* c_buf = (float*)(ws + off);            off += TB * H_DIM * 4;            // 128 MiB
    unsigned int* Wb = (unsigned int*)(ws + off); off += (size_t)(K_DIM / 2) * G_DIM * 4;
    unsigned long long* Wq = (unsigned long long*)(ws + off); off += (size_t)(K_DIM / 4) * G_DIM * 8;
    float* bias = (float*)(ws + off);             off += (size_t)G_DIM * 4;
    int* kmap    = (int*)(ws + off);              off += TB * 4;
    int* rowlist = (int*)(ws + off);              off += TB * 4;
    int* counts  = (int*)(ws + off);              off += 256;
    int* offs    = (int*)(ws + off);              off += 256;
    int* bcnt    = (int*)(ws + off);              off += (size_t)T_DIM * NROUNDS * 4;  // 80 KiB
    int* boffs   = (int*)(ws + off);              off += (size_t)T_DIM * NROUNDS * 4;  // 80 KiB
    short* ab = (short*)(ws + off);               off += TB * 512 * 2;                 // 128 MiB

    k_prep_weights<<<1024, 256, 0, stream>>>(W_ih, W_hh, b_ih, b_hh, Wb, bias);
    k_prep_wq<<<512, 256, 0, stream>>>(W_ih, W_hh, Wq);
    k_prep_ab<<<(int)(TB * 64 / 256), 256, 0, stream>>>(x, (unsigned long long*)ab);
    k_prefill<<<(int)(TB * 32 / 256), 256, 0, stream>>>(h0, done, (unsigned long long*)ab);
    k_kmap<<<T_DIM, 256, 0, stream>>>(done, kmap, bcnt);
    k_scan<<<1, 512, 0, stream>>>(bcnt, boffs, counts, offs);
    k_scatter<<<(int)(TB / 256), 256, 0, stream>>>(kmap, offs, boffs, rowlist);

    int est = 70000;   // statistical upper bound on round-0 rows; ~halves each round
    for (int k = 0; k < CHAIN_K; ++k) {
        int rch = (est + 31) / 32;
        if (rch > 32) rch = 32;
        if (rch < 1) rch = 1;
        k_round<<<8 * rch, 512, 0, stream>>>((const short*)ab, c0, done, (const short*)Wb,
                                             bias, counts, offs, rowlist, out, c_buf, ab, k);
        est >>= 1;
    }
    k_finish<<<64, 1024, 0, stream>>>(x, Wq, bias, counts, offs, rowlist, kmap, out, c_buf);
    k_final<<<B_DIM * H_DIM / 256, 256, 0, stream>>>(c_buf, out);
}